// Round 22
// baseline (72.654 us; speedup 1.0000x reference)
//
#include <hip/hip_runtime.h>
#include <hip/hip_cooperative_groups.h>
#include <math.h>

#define NK 32           // knots
#define NP 36           // NK + 4 (system size)
#define PX 16           // pixels per thread (two 8-px chunks of 4 pairs)
#define WSN 68          // float4 per batch in ws: [0..35]=W, [36..67]=knots

typedef float v2f __attribute__((ext_vector_type(2)));

// hardware v_sqrt_f32 (~1 ulp) — __sqrtf collides with glibc math.h macros
__device__ __forceinline__ float hw_sqrtf(float x) {
    return __builtin_amdgcn_sqrtf(x);
}

// broadcast float from lane sl (literal at call sites) — pure bit ops
__device__ __forceinline__ float bcastf(float v, int sl) {
    return __int_as_float(__builtin_amdgcn_readlane(__float_as_int(v), sl));
}

// packed fma helpers (lower to v_pk_fma_f32)
__device__ __forceinline__ v2f pks(float s, v2f b, v2f c) {
    return __builtin_elementwise_fma((v2f){s, s}, b, c);
}
__device__ __forceinline__ v2f pkv(v2f a, v2f b, v2f c) {
    return __builtin_elementwise_fma(a, b, c);
}

// ---------------------------------------------------------------------------
// Spline-apply: one chunk of 4 pixel-pairs (8 px, 24 floats), packed-f32.
// (verbatim from R19 — passed at absmax 0.25, best time 32.6us)
// ---------------------------------------------------------------------------
__device__ __forceinline__ void apply_chunk8(const float4* __restrict__ src,
                                             float4* __restrict__ dst,
                                             const float4* __restrict__ sX,
                                             const float4* __restrict__ sW4,
                                             float4 wb, float4 w33,
                                             float4 w34, float4 w35) {
    float4 v0 = src[0], v1 = src[1], v2 = src[2],
           v3 = src[3], v4 = src[4], v5 = src[5];
    float f[24] = {v0.x, v0.y, v0.z, v0.w, v1.x, v1.y, v1.z, v1.w,
                   v2.x, v2.y, v2.z, v2.w, v3.x, v3.y, v3.z, v3.w,
                   v4.x, v4.y, v4.z, v4.w, v5.x, v5.y, v5.z, v5.w};

    v2f fx[4], fy[4], fz[4], pn[4];
    #pragma unroll
    for (int q = 0; q < 4; ++q) {
        fx[q] = (v2f){f[6*q+0], f[6*q+3]};
        fy[q] = (v2f){f[6*q+1], f[6*q+4]};
        fz[q] = (v2f){f[6*q+2], f[6*q+5]};
        pn[q] = pkv(fz[q], fz[q], pkv(fy[q], fy[q], fx[q] * fx[q]));
    }

    v2f ax[4], ay[4], az[4];
    #pragma unroll
    for (int q = 0; q < 4; ++q) {
        ax[q] = pks(w35.x, fz[q], pks(w34.x, fy[q], pks(w33.x, fx[q], (v2f){wb.x, wb.x})));
        ay[q] = pks(w35.y, fz[q], pks(w34.y, fy[q], pks(w33.y, fx[q], (v2f){wb.y, wb.y})));
        az[q] = pks(w35.z, fz[q], pks(w34.z, fy[q], pks(w33.z, fx[q], (v2f){wb.z, wb.z})));
    }

    #pragma unroll 4
    for (int k = 0; k < NK; ++k) {
        float4 xk = sX[k];
        float4 wk = sW4[k];
        #pragma unroll
        for (int q = 0; q < 4; ++q) {
            v2f t = pn[q] + (v2f){xk.w, xk.w};
            t = pks(xk.x, fx[q], t);
            t = pks(xk.y, fy[q], t);
            t = pks(xk.z, fz[q], t);
            t = __builtin_elementwise_max(t, (v2f){0.f, 0.f});
            v2f d = (v2f){hw_sqrtf(t[0]), hw_sqrtf(t[1])};
            ax[q] = pks(wk.x, d, ax[q]);
            ay[q] = pks(wk.y, d, ay[q]);
            az[q] = pks(wk.z, d, az[q]);
        }
    }

    #pragma unroll
    for (int u = 0; u < 2; ++u) {
        int a = 2*u, c = 2*u + 1;
        dst[3*u+0] = make_float4(ax[a][0], ay[a][0], az[a][0], ax[a][1]);
        dst[3*u+1] = make_float4(ay[a][1], az[a][1], ax[c][0], ay[c][0]);
        dst[3*u+2] = make_float4(az[c][0], ax[c][1], ay[c][1], az[c][1]);
    }
}

// ---------------------------------------------------------------------------
// COOPERATIVE kernel: block (0, b) solves batch b's 3 systems (R16-proven
// no-pivot fp32 GJ) and publishes W + knot table to workspace; grid sync;
// all blocks load the tables and run the packed apply. Removes the 49x
// per-batch solve duplication that cost ~5-7us/SIMD in the fused version.
// 392 blocks <= 512 co-residency capacity at 2 blocks/CU.
// ---------------------------------------------------------------------------
__global__ __launch_bounds__(256, 2) void tps_coop(const float* __restrict__ raw,
                                                   const float* __restrict__ params,
                                                   float* __restrict__ out,
                                                   float4* __restrict__ ws,
                                                   int HW) {
    __shared__ float  sxs[NK * 3];
    __shared__ float4 sX[NK];      // (-2x0, -2x1, -2x2, |x|^2)
    __shared__ float4 sW4[NP];

    int b   = blockIdx.y;
    int tid = threadIdx.x;
    const float* pp = params + (size_t)b * (6 * NK + 3);
    float4* wsb = ws + (size_t)b * WSN;

    if (blockIdx.x == 0) {
        // =================== solver block for batch b ===================
        if (tid < NK * 3) sxs[tid] = pp[tid];
        __syncthreads();

        int wid  = tid >> 6;
        int lane = tid & 63;

        if (wid < 3) {
            int ch = wid;
            float lam = pp[6 * NK + ch];

            int li = (lane < NK) ? lane : 0;
            float myx0 = sxs[li*3+0], myx1 = sxs[li*3+1], myx2 = sxs[li*3+2];

            float rr0,rr1,rr2,rr3,rr4,rr5,rr6,rr7,rr8,rr9,rr10,rr11,rr12,
                  rr13,rr14,rr15,rr16,rr17,rr18,rr19,rr20,rr21,rr22,rr23,
                  rr24,rr25,rr26,rr27,rr28,rr29,rr30,rr31,rr32,rr33,rr34,
                  rr35,rr36;

            float bcomp = (lane == 33) ? 0.f : (lane == 34) ? 1.f : 2.f;
#define BUILDC(c) do {                                                        \
    float xc0 = sxs[(c)*3+0], xc1 = sxs[(c)*3+1], xc2 = sxs[(c)*3+2];         \
    float dx = myx0 - xc0, dy = myx1 - xc1, dz = myx2 - xc2;                  \
    float d  = hw_sqrtf(dx*dx + dy*dy + dz*dz);                               \
    float v;                                                                  \
    if (lane < NK)       v = (lane == (c)) ? lam : d;                         \
    else if (lane == 32) v = 1.0f;                                            \
    else if (lane < NP)  v = (bcomp==0.f)?xc0:(bcomp==1.f)?xc1:xc2;           \
    else                 v = 0.0f;                                            \
    rr##c = v;                                                                \
} while (0)
            BUILDC(0);  BUILDC(1);  BUILDC(2);  BUILDC(3);  BUILDC(4);
            BUILDC(5);  BUILDC(6);  BUILDC(7);  BUILDC(8);  BUILDC(9);
            BUILDC(10); BUILDC(11); BUILDC(12); BUILDC(13); BUILDC(14);
            BUILDC(15); BUILDC(16); BUILDC(17); BUILDC(18); BUILDC(19);
            BUILDC(20); BUILDC(21); BUILDC(22); BUILDC(23); BUILDC(24);
            BUILDC(25); BUILDC(26); BUILDC(27); BUILDC(28); BUILDC(29);
            BUILDC(30); BUILDC(31);
#undef BUILDC
            bool top = (lane < NK);
            rr32 = top ? 1.0f : 0.0f;
            rr33 = top ? myx0 : 0.0f;
            rr34 = top ? myx1 : 0.0f;
            rr35 = top ? myx2 : 0.0f;
            rr36 = top ? pp[3*NK + li*3 + ch] : 0.0f;   // rhs = ys[lane][ch]

#define COLU(c) if ((c) > KK) { rr##c -= minv * bcastf(rr##c, KK); }
#define ALLCOLS \
    COLU(1)  COLU(2)  COLU(3)  COLU(4)  COLU(5)  COLU(6)  COLU(7)  COLU(8)  \
    COLU(9)  COLU(10) COLU(11) COLU(12) COLU(13) COLU(14) COLU(15) COLU(16) \
    COLU(17) COLU(18) COLU(19) COLU(20) COLU(21) COLU(22) COLU(23) COLU(24) \
    COLU(25) COLU(26) COLU(27) COLU(28) COLU(29) COLU(30) COLU(31) COLU(32) \
    COLU(33) COLU(34) COLU(35) COLU(36)
#define STEP(Kv) do {                                                         \
    const int KK = (Kv);                                                      \
    float pv  = bcastf(rr##Kv, (Kv));                                         \
    float inv = __builtin_amdgcn_rcpf(pv);                                    \
    bool  isp = (lane == (Kv));                                               \
    float minv = isp ? (1.0f - inv) : rr##Kv * inv;                           \
    ALLCOLS                                                                   \
} while (0)

            STEP(0);  STEP(1);  STEP(2);  STEP(3);  STEP(4);  STEP(5);
            STEP(6);  STEP(7);  STEP(8);  STEP(9);  STEP(10); STEP(11);
            STEP(12); STEP(13); STEP(14); STEP(15); STEP(16); STEP(17);
            STEP(18); STEP(19); STEP(20); STEP(21); STEP(22); STEP(23);
            STEP(24); STEP(25); STEP(26); STEP(27); STEP(28); STEP(29);
            STEP(30); STEP(31); STEP(32); STEP(33); STEP(34); STEP(35);
#undef STEP
#undef ALLCOLS
#undef COLU

            if (lane < NP)
                ((float*)&wsb[lane])[ch] = rr36;   // word-granular: no race
        } else {
            // wave 3: knot table as (-2x, |x|^2)
            if (lane < NK) {
                float x0 = sxs[lane*3+0], x1 = sxs[lane*3+1], x2 = sxs[lane*3+2];
                wsb[NP + lane] = make_float4(-2.f*x0, -2.f*x1, -2.f*x2,
                                             x0*x0 + x1*x1 + x2*x2);
            }
        }
    }

    cooperative_groups::this_grid().sync();

    // ---- all blocks: load W + knot tables from workspace ----
    if (tid < NP)            sW4[tid]      = wsb[tid];
    else if (tid < NP + NK)  sX[tid - NP]  = wsb[tid];
    __syncthreads();

    // ============ apply, PX=16 in two 8-px chunks (R19 verbatim) =========
    int p16 = blockIdx.x * 256 + tid;          // 16-px group, grid exact
    size_t base = (size_t)b * HW * 3 + (size_t)p16 * (PX * 3);

    float4 wb  = sW4[NK];
    float4 w33 = sW4[NK+1], w34 = sW4[NK+2], w35 = sW4[NK+3];

    apply_chunk8((const float4*)(raw + base),      (float4*)(out + base),
                 sX, sW4, wb, w33, w34, w35);
    apply_chunk8((const float4*)(raw + base + 24), (float4*)(out + base + 24),
                 sX, sW4, wb, w33, w34, w35);
}

extern "C" void kernel_launch(void* const* d_in, const int* in_sizes, int n_in,
                              void* d_out, int out_size, void* d_ws, size_t ws_size,
                              hipStream_t stream) {
    const float* raw    = (const float*)d_in[0];
    const float* params = (const float*)d_in[1];
    float* out  = (float*)d_out;
    float4* ws  = (float4*)d_ws;               // 8 batches x 68 float4 = 8.7KB

    int B  = in_sizes[1] / (6 * NK + 3);
    int HW = in_sizes[0] / (B * 3);

    int groups = HW / PX;                      // 200704/16 = 12544
    int bpb = (groups + 255) / 256;            // 49 blocks per batch, exact

    dim3 grid(bpb, B), block(256);
    void* args[] = {(void*)&raw, (void*)&params, (void*)&out,
                    (void*)&ws, (void*)&HW};
    hipLaunchCooperativeKernel((const void*)tps_coop, grid, block,
                               args, 0, stream);
}

// Round 23
// 31.787 us; speedup vs baseline: 2.2857x; 2.2857x over previous
//
#include <hip/hip_runtime.h>
#include <math.h>

#define NK 32           // knots
#define NP 36           // NK + 4 (system size)
#define PX 8            // pixels per thread (one 4-pair chunk)

typedef float v2f __attribute__((ext_vector_type(2)));

// hardware v_sqrt_f32 (~1 ulp) — __sqrtf collides with glibc math.h macros
__device__ __forceinline__ float hw_sqrtf(float x) {
    return __builtin_amdgcn_sqrtf(x);
}

// broadcast float from lane sl (literal at call sites) — pure bit ops
__device__ __forceinline__ float bcastf(float v, int sl) {
    return __int_as_float(__builtin_amdgcn_readlane(__float_as_int(v), sl));
}

// packed fma helpers (lower to v_pk_fma_f32)
__device__ __forceinline__ v2f pks(float s, v2f b, v2f c) {
    return __builtin_elementwise_fma((v2f){s, s}, b, c);
}
__device__ __forceinline__ v2f pkv(v2f a, v2f b, v2f c) {
    return __builtin_elementwise_fma(a, b, c);
}

// ---------------------------------------------------------------------------
// Spline-apply: one chunk of 4 pixel-pairs (8 px, 24 floats), packed-f32.
// (verbatim from R19 — passed at absmax 0.25)
// ---------------------------------------------------------------------------
__device__ __forceinline__ void apply_chunk8(const float4* __restrict__ src,
                                             float4* __restrict__ dst,
                                             const float4* __restrict__ sX,
                                             const float4* __restrict__ sW4,
                                             float4 wb, float4 w33,
                                             float4 w34, float4 w35) {
    float4 v0 = src[0], v1 = src[1], v2 = src[2],
           v3 = src[3], v4 = src[4], v5 = src[5];
    float f[24] = {v0.x, v0.y, v0.z, v0.w, v1.x, v1.y, v1.z, v1.w,
                   v2.x, v2.y, v2.z, v2.w, v3.x, v3.y, v3.z, v3.w,
                   v4.x, v4.y, v4.z, v4.w, v5.x, v5.y, v5.z, v5.w};

    v2f fx[4], fy[4], fz[4], pn[4];
    #pragma unroll
    for (int q = 0; q < 4; ++q) {
        fx[q] = (v2f){f[6*q+0], f[6*q+3]};
        fy[q] = (v2f){f[6*q+1], f[6*q+4]};
        fz[q] = (v2f){f[6*q+2], f[6*q+5]};
        pn[q] = pkv(fz[q], fz[q], pkv(fy[q], fy[q], fx[q] * fx[q]));
    }

    v2f ax[4], ay[4], az[4];
    #pragma unroll
    for (int q = 0; q < 4; ++q) {
        ax[q] = pks(w35.x, fz[q], pks(w34.x, fy[q], pks(w33.x, fx[q], (v2f){wb.x, wb.x})));
        ay[q] = pks(w35.y, fz[q], pks(w34.y, fy[q], pks(w33.y, fx[q], (v2f){wb.y, wb.y})));
        az[q] = pks(w35.z, fz[q], pks(w34.z, fy[q], pks(w33.z, fx[q], (v2f){wb.z, wb.z})));
    }

    // knot loop: d^2 = |f|^2 + (-2x)·f + |x|^2 (packed), then sqrt per lane
    #pragma unroll 4
    for (int k = 0; k < NK; ++k) {
        float4 xk = sX[k];
        float4 wk = sW4[k];
        #pragma unroll
        for (int q = 0; q < 4; ++q) {
            v2f t = pn[q] + (v2f){xk.w, xk.w};
            t = pks(xk.x, fx[q], t);
            t = pks(xk.y, fy[q], t);
            t = pks(xk.z, fz[q], t);
            t = __builtin_elementwise_max(t, (v2f){0.f, 0.f});
            v2f d = (v2f){hw_sqrtf(t[0]), hw_sqrtf(t[1])};
            ax[q] = pks(wk.x, d, ax[q]);
            ay[q] = pks(wk.y, d, ay[q]);
            az[q] = pks(wk.z, d, az[q]);
        }
    }

    // repack: each unit of 2 pairs (4 px, 12 floats) -> 3 float4 stores
    #pragma unroll
    for (int u = 0; u < 2; ++u) {
        int a = 2*u, c = 2*u + 1;
        dst[3*u+0] = make_float4(ax[a][0], ay[a][0], az[a][0], ax[a][1]);
        dst[3*u+1] = make_float4(ay[a][1], az[a][1], ax[c][0], ay[c][0]);
        dst[3*u+2] = make_float4(az[c][0], ax[c][1], ay[c][1], az[c][1]);
    }
}

// ---------------------------------------------------------------------------
// FUSED kernel, 512-thread blocks: SAME 392 blocks / 392 solves / total
// apply instructions as R19 (32.6us best), but 8 waves per block -> ~3
// waves/SIMD instead of 1.5, doubling wave-level latency hiding for the
// sqrt/FMA chains. Waves 0..2 solve (R16-proven no-pivot fp32 GJ), wave 3
// builds the knot table, waves 4..7 go straight to the barrier.
// ---------------------------------------------------------------------------
__global__ __launch_bounds__(512, 2) void tps_fused(const float* __restrict__ raw,
                                                    const float* __restrict__ params,
                                                    float* __restrict__ out,
                                                    int HW) {
    __shared__ float  sxs[NK * 3];
    __shared__ float4 sX[NK];      // (-2x0, -2x1, -2x2, |x|^2)
    __shared__ float4 sW4[NP];

    int b   = blockIdx.y;
    int tid = threadIdx.x;
    const float* pp = params + (size_t)b * (6 * NK + 3);

    if (tid < NK * 3) sxs[tid] = pp[tid];
    __syncthreads();

    int wid  = tid >> 6;
    int lane = tid & 63;

    if (wid < 3) {
        // ========== Phase 1: solve channel `wid` (R16 verbatim) ==========
        int ch = wid;
        float lam = pp[6 * NK + ch];

        int li = (lane < NK) ? lane : 0;
        float myx0 = sxs[li*3+0], myx1 = sxs[li*3+1], myx2 = sxs[li*3+2];

        float rr0,rr1,rr2,rr3,rr4,rr5,rr6,rr7,rr8,rr9,rr10,rr11,rr12,rr13,
              rr14,rr15,rr16,rr17,rr18,rr19,rr20,rr21,rr22,rr23,rr24,rr25,
              rr26,rr27,rr28,rr29,rr30,rr31,rr32,rr33,rr34,rr35,rr36;

        float bcomp = (lane == 33) ? 0.f : (lane == 34) ? 1.f : 2.f;
#define BUILDC(c) do {                                                        \
    float xc0 = sxs[(c)*3+0], xc1 = sxs[(c)*3+1], xc2 = sxs[(c)*3+2];         \
    float dx = myx0 - xc0, dy = myx1 - xc1, dz = myx2 - xc2;                  \
    float d  = hw_sqrtf(dx*dx + dy*dy + dz*dz);                               \
    float v;                                                                  \
    if (lane < NK)       v = (lane == (c)) ? lam : d;                         \
    else if (lane == 32) v = 1.0f;                                            \
    else if (lane < NP)  v = (bcomp==0.f)?xc0:(bcomp==1.f)?xc1:xc2;           \
    else                 v = 0.0f;                                            \
    rr##c = v;                                                                \
} while (0)
        BUILDC(0);  BUILDC(1);  BUILDC(2);  BUILDC(3);  BUILDC(4);  BUILDC(5);
        BUILDC(6);  BUILDC(7);  BUILDC(8);  BUILDC(9);  BUILDC(10); BUILDC(11);
        BUILDC(12); BUILDC(13); BUILDC(14); BUILDC(15); BUILDC(16); BUILDC(17);
        BUILDC(18); BUILDC(19); BUILDC(20); BUILDC(21); BUILDC(22); BUILDC(23);
        BUILDC(24); BUILDC(25); BUILDC(26); BUILDC(27); BUILDC(28); BUILDC(29);
        BUILDC(30); BUILDC(31);
#undef BUILDC
        bool top = (lane < NK);
        rr32 = top ? 1.0f : 0.0f;
        rr33 = top ? myx0 : 0.0f;
        rr34 = top ? myx1 : 0.0f;
        rr35 = top ? myx2 : 0.0f;
        rr36 = top ? pp[3*NK + li*3 + ch] : 0.0f;   // rhs = ys[lane][ch]

#define COLU(c) if ((c) > KK) { rr##c -= minv * bcastf(rr##c, KK); }
#define ALLCOLS \
    COLU(1)  COLU(2)  COLU(3)  COLU(4)  COLU(5)  COLU(6)  COLU(7)  COLU(8)  \
    COLU(9)  COLU(10) COLU(11) COLU(12) COLU(13) COLU(14) COLU(15) COLU(16) \
    COLU(17) COLU(18) COLU(19) COLU(20) COLU(21) COLU(22) COLU(23) COLU(24) \
    COLU(25) COLU(26) COLU(27) COLU(28) COLU(29) COLU(30) COLU(31) COLU(32) \
    COLU(33) COLU(34) COLU(35) COLU(36)
#define STEP(Kv) do {                                                         \
    const int KK = (Kv);                                                      \
    float pv  = bcastf(rr##Kv, (Kv));                                         \
    float inv = __builtin_amdgcn_rcpf(pv);                                    \
    bool  isp = (lane == (Kv));                                               \
    float minv = isp ? (1.0f - inv) : rr##Kv * inv;                           \
    ALLCOLS                                                                   \
} while (0)

        STEP(0);  STEP(1);  STEP(2);  STEP(3);  STEP(4);  STEP(5);
        STEP(6);  STEP(7);  STEP(8);  STEP(9);  STEP(10); STEP(11);
        STEP(12); STEP(13); STEP(14); STEP(15); STEP(16); STEP(17);
        STEP(18); STEP(19); STEP(20); STEP(21); STEP(22); STEP(23);
        STEP(24); STEP(25); STEP(26); STEP(27); STEP(28); STEP(29);
        STEP(30); STEP(31); STEP(32); STEP(33); STEP(34); STEP(35);
#undef STEP
#undef ALLCOLS
#undef COLU

        if (lane < NP)
            ((float*)&sW4[lane])[ch] = rr36;   // per-ch component: no race
    } else if (wid == 3) {
        // wave 3: knot table as (-2x, |x|^2) for dot-form distance
        if (lane < NK) {
            float x0 = sxs[lane*3+0], x1 = sxs[lane*3+1], x2 = sxs[lane*3+2];
            sX[lane] = make_float4(-2.f*x0, -2.f*x1, -2.f*x2,
                                   x0*x0 + x1*x1 + x2*x2);
        }
    }
    // waves 4..7: straight to the barrier
    __syncthreads();

    // ============ Phase 2: apply, PX=8 (one 4-pair chunk) ================
    int p8 = blockIdx.x * 512 + tid;           // 8-px group, grid exact
    size_t base = (size_t)b * HW * 3 + (size_t)p8 * (PX * 3);

    float4 wb  = sW4[NK];
    float4 w33 = sW4[NK+1], w34 = sW4[NK+2], w35 = sW4[NK+3];

    apply_chunk8((const float4*)(raw + base), (float4*)(out + base),
                 sX, sW4, wb, w33, w34, w35);
}

extern "C" void kernel_launch(void* const* d_in, const int* in_sizes, int n_in,
                              void* d_out, int out_size, void* d_ws, size_t ws_size,
                              hipStream_t stream) {
    const float* raw    = (const float*)d_in[0];
    const float* params = (const float*)d_in[1];
    float* out = (float*)d_out;

    int B  = in_sizes[1] / (6 * NK + 3);
    int HW = in_sizes[0] / (B * 3);

    int groups = HW / PX;                      // 200704/8 = 25088
    int bpb = (groups + 511) / 512;            // 49 blocks per batch, exact
    tps_fused<<<dim3(bpb, B), dim3(512), 0, stream>>>(raw, params, out, HW);
}